// Round 1
// baseline (5880.886 us; speedup 1.0000x reference)
//
#include <hip/hip_runtime.h>
#include <hip/hip_bf16.h>
#include <math.h>

// ---------------- small utility kernels ----------------

__global__ void k_fill(float* __restrict__ p, float v, int n) {
    int i = blockIdx.x * 256 + threadIdx.x;
    if (i < n) p[i] = v;
}

__global__ void k_deg(const int* __restrict__ dst, float* __restrict__ deg, int E) {
    int i = blockIdx.x * 256 + threadIdx.x;
    if (i < E) atomicAdd(&deg[dst[i]], 1.0f);
}

__global__ void k_rsqrt_inplace(float* __restrict__ p, int n) {
    int i = blockIdx.x * 256 + threadIdx.x;
    if (i < n) p[i] = rsqrtf(p[i]);
}

// ---------------- fp32 GEMM: C[M,256] = A[M,256] @ B[256,256] ----------------
// 64x64 block tile, BK=16, 256 threads, 4x4 microtile per thread.

__global__ __launch_bounds__(256) void k_gemm256(const float* __restrict__ A,
                                                 const float* __restrict__ B,
                                                 float* __restrict__ C, int M) {
    __shared__ float As[16][68];
    __shared__ float Bs[16][68];
    const int bm = blockIdx.x;
    const int bn = blockIdx.y;          // 0..3
    const int t  = threadIdx.x;
    const int ty = t >> 4, tx = t & 15;
    const int row0 = bm * 64;

    const int ar = t >> 2;              // 0..63   A tile row
    const int ac = (t & 3) * 4;         // 0,4,8,12 A tile col (float4)
    const int br = t >> 4;              // 0..15   B tile row
    const int bc = (t & 15) * 4;        // B tile col (float4)

    float acc[4][4] = {};

    for (int k0 = 0; k0 < 256; k0 += 16) {
        float4 av = make_float4(0.f, 0.f, 0.f, 0.f);
        int arow = row0 + ar;
        if (arow < M) av = *(const float4*)(A + (size_t)arow * 256 + k0 + ac);
        As[ac + 0][ar] = av.x;
        As[ac + 1][ar] = av.y;
        As[ac + 2][ar] = av.z;
        As[ac + 3][ar] = av.w;

        float4 bv = *(const float4*)(B + (size_t)(k0 + br) * 256 + bn * 64 + bc);
        *(float4*)(&Bs[br][bc]) = bv;

        __syncthreads();
#pragma unroll
        for (int k = 0; k < 16; ++k) {
            float a[4], b[4];
#pragma unroll
            for (int i = 0; i < 4; ++i) a[i] = As[k][ty * 4 + i];
#pragma unroll
            for (int j = 0; j < 4; ++j) b[j] = Bs[k][tx * 4 + j];
#pragma unroll
            for (int i = 0; i < 4; ++i)
#pragma unroll
                for (int j = 0; j < 4; ++j) acc[i][j] += a[i] * b[j];
        }
        __syncthreads();
    }

#pragma unroll
    for (int i = 0; i < 4; ++i) {
        int r = row0 + ty * 4 + i;
        if (r < M) {
            float4 v = make_float4(acc[i][0], acc[i][1], acc[i][2], acc[i][3]);
            *(float4*)(C + (size_t)r * 256 + bn * 64 + tx * 4) = v;
        }
    }
}

// ---------------- agg init: AGG[i,:] = H[i,:] * dis[i]^2 ----------------

__global__ void k_scale_rows(const float* __restrict__ H, const float* __restrict__ dis,
                             float* __restrict__ AGG, int n) {
    int idx = blockIdx.x * 256 + threadIdx.x;   // one float4 per thread
    int total = n * 64;
    if (idx >= total) return;
    int row = idx >> 6;
    float s = dis[row];
    s = s * s;
    float4 v = ((const float4*)H)[idx];
    v.x *= s; v.y *= s; v.z *= s; v.w *= s;
    ((float4*)AGG)[idx] = v;
}

// ---------------- full 256-feature edge aggregation ----------------
// one wave per edge: gather H[src] row (float4/lane), atomicAdd into AGG[dst]

__global__ __launch_bounds__(256) void k_edge_agg(const int* __restrict__ src,
                                                  const int* __restrict__ dst,
                                                  const float* __restrict__ dis,
                                                  const float* __restrict__ H,
                                                  float* __restrict__ AGG, int E) {
    int wid  = (blockIdx.x * 256 + threadIdx.x) >> 6;
    int lane = threadIdx.x & 63;
    if (wid >= E) return;
    int s = src[wid], d = dst[wid];
    float nrm = dis[s] * dis[d];
    float4 v = ((const float4*)(H + (size_t)s * 256))[lane];
    float* ad = AGG + (size_t)d * 256 + lane * 4;
    atomicAdd(ad + 0, v.x * nrm);
    atomicAdd(ad + 1, v.y * nrm);
    atomicAdd(ad + 2, v.z * nrm);
    atomicAdd(ad + 3, v.w * nrm);
}

// ---------------- post-activation layer0: t_i, d_i (h0 never stored) ----------------

__global__ __launch_bounds__(256) void k_postact0(const float* __restrict__ AGG,
                                                  const float* __restrict__ b0,
                                                  const float* __restrict__ attnW,
                                                  const float* __restrict__ attnB,
                                                  const float* __restrict__ hw,
                                                  float* __restrict__ t,
                                                  float* __restrict__ dvec, int n) {
    int wid  = (blockIdx.x * 256 + threadIdx.x) >> 6;
    int lane = threadIdx.x & 63;
    if (wid >= n) return;
    float4 v  = ((const float4*)(AGG + (size_t)wid * 256))[lane];
    float4 bb = ((const float4*)b0)[lane];
    v.x = fmaxf(v.x + bb.x, 0.f);
    v.y = fmaxf(v.y + bb.y, 0.f);
    v.z = fmaxf(v.z + bb.z, 0.f);
    v.w = fmaxf(v.w + bb.w, 0.f);
    float4 aw = ((const float4*)attnW)[lane];
    float4 hv = ((const float4*)hw)[lane];
    float tp = v.x * aw.x + v.y * aw.y + v.z * aw.z + v.w * aw.w;
    float dp = v.x * hv.x + v.y * hv.y + v.z * hv.z + v.w * hv.w;
#pragma unroll
    for (int o = 32; o >= 1; o >>= 1) {
        tp += __shfl_down(tp, o);
        dp += __shfl_down(dp, o);
    }
    if (lane == 0) {
        t[wid]    = tp + attnB[0];
        dvec[wid] = dp;
    }
}

// ---------------- global softmax over N (two-stage max, two-stage sum) ----------------

__global__ __launch_bounds__(256) void k_max1(const float* __restrict__ t,
                                              float* __restrict__ partial, int n) {
    __shared__ float sm[256];
    float m = -INFINITY;
    for (int i = blockIdx.x * 256 + threadIdx.x; i < n; i += 256 * 256)
        m = fmaxf(m, t[i]);
    sm[threadIdx.x] = m;
    __syncthreads();
    for (int s = 128; s > 0; s >>= 1) {
        if (threadIdx.x < s) sm[threadIdx.x] = fmaxf(sm[threadIdx.x], sm[threadIdx.x + s]);
        __syncthreads();
    }
    if (threadIdx.x == 0) partial[blockIdx.x] = sm[0];
}

__global__ __launch_bounds__(256) void k_max2(const float* __restrict__ partial,
                                              float* __restrict__ M) {
    __shared__ float sm[256];
    sm[threadIdx.x] = partial[threadIdx.x];
    __syncthreads();
    for (int s = 128; s > 0; s >>= 1) {
        if (threadIdx.x < s) sm[threadIdx.x] = fmaxf(sm[threadIdx.x], sm[threadIdx.x + s]);
        __syncthreads();
    }
    if (threadIdx.x == 0) *M = sm[0];
}

__global__ __launch_bounds__(256) void k_sum1(const float* __restrict__ t,
                                              const float* __restrict__ M,
                                              float* __restrict__ partial, int n) {
    __shared__ float sm[256];
    float m = *M;
    float s0 = 0.f;
    for (int i = blockIdx.x * 256 + threadIdx.x; i < n; i += 256 * 256)
        s0 += expf(t[i] - m);
    sm[threadIdx.x] = s0;
    __syncthreads();
    for (int s = 128; s > 0; s >>= 1) {
        if (threadIdx.x < s) sm[threadIdx.x] += sm[threadIdx.x + s];
        __syncthreads();
    }
    if (threadIdx.x == 0) partial[blockIdx.x] = sm[0];
}

__global__ __launch_bounds__(256) void k_sum2(const float* __restrict__ partial,
                                              float* __restrict__ S) {
    __shared__ float sm[256];
    sm[threadIdx.x] = partial[threadIdx.x];
    __syncthreads();
    for (int s = 128; s > 0; s >>= 1) {
        if (threadIdx.x < s) sm[threadIdx.x] += sm[threadIdx.x + s];
        __syncthreads();
    }
    if (threadIdx.x == 0) *S = sm[0];
}

// z_i = softmax_i * d_i ; zagg_i = z_i * dis_i^2 (self-loop init)
__global__ void k_z(const float* __restrict__ t, const float* __restrict__ dvec,
                    const float* __restrict__ dis, const float* __restrict__ M,
                    const float* __restrict__ S, float* __restrict__ z,
                    float* __restrict__ zagg, int n) {
    int i = blockIdx.x * 256 + threadIdx.x;
    if (i >= n) return;
    float zi = expf(t[i] - *M) / *S * dvec[i];
    z[i] = zi;
    float di = dis[i];
    zagg[i] = zi * di * di;
}

__global__ void k_edge_scalar(const int* __restrict__ src, const int* __restrict__ dst,
                              const float* __restrict__ dis, const float* __restrict__ z,
                              float* __restrict__ zagg, int E) {
    int e = blockIdx.x * 256 + threadIdx.x;
    if (e >= E) return;
    int s = src[e], d = dst[e];
    atomicAdd(&zagg[d], z[s] * dis[s] * dis[d]);
}

// h1[i,j] = relu(zagg[i]*W1[j] + b1[j])
__global__ void k_h1(const float* __restrict__ zagg, const float* __restrict__ W1,
                     const float* __restrict__ b1, float* __restrict__ H1, int n) {
    int idx = blockIdx.x * 256 + threadIdx.x;   // one float4 per thread
    int total = n * 64;
    if (idx >= total) return;
    int row = idx >> 6, lane = idx & 63;
    float s = zagg[row];
    float4 w  = ((const float4*)W1)[lane];
    float4 bb = ((const float4*)b1)[lane];
    float4 v;
    v.x = fmaxf(s * w.x + bb.x, 0.f);
    v.y = fmaxf(s * w.y + bb.y, 0.f);
    v.z = fmaxf(s * w.z + bb.z, 0.f);
    v.w = fmaxf(s * w.w + bb.w, 0.f);
    ((float4*)H1)[idx] = v;
}

// relu(AGG + b2) then mean-pool accumulate via atomics
__global__ __launch_bounds__(256) void k_pool(const float* __restrict__ AGG,
                                              const float* __restrict__ b2,
                                              const int* __restrict__ batch,
                                              float* __restrict__ pooled,
                                              float* __restrict__ cnt, int n) {
    int wid  = (blockIdx.x * 256 + threadIdx.x) >> 6;
    int lane = threadIdx.x & 63;
    if (wid >= n) return;
    float4 v  = ((const float4*)(AGG + (size_t)wid * 256))[lane];
    float4 bb = ((const float4*)b2)[lane];
    v.x = fmaxf(v.x + bb.x, 0.f);
    v.y = fmaxf(v.y + bb.y, 0.f);
    v.z = fmaxf(v.z + bb.z, 0.f);
    v.w = fmaxf(v.w + bb.w, 0.f);
    int g = batch[wid];
    float* pg = pooled + (size_t)g * 256 + lane * 4;
    atomicAdd(pg + 0, v.x);
    atomicAdd(pg + 1, v.y);
    atomicAdd(pg + 2, v.z);
    atomicAdd(pg + 3, v.w);
    if (lane == 0) atomicAdd(&cnt[g], 1.0f);
}

// per-graph: logits = (pooled/cnt) @ W_out + b_out ; log_softmax
__global__ __launch_bounds__(64) void k_final(const float* __restrict__ pooled,
                                              const float* __restrict__ cnt,
                                              const float* __restrict__ Wout,
                                              const float* __restrict__ bout,
                                              float* __restrict__ out, int ngraphs) {
    int g = blockIdx.x;
    if (g >= ngraphs) return;
    int lane = threadIdx.x;
    float inv = 1.0f / fmaxf(cnt[g], 1.0f);
    float4 p = ((const float4*)(pooled + (size_t)g * 256))[lane];
    p.x *= inv; p.y *= inv; p.z *= inv; p.w *= inv;
    __shared__ float logits[16];
    for (int j = 0; j < 16; ++j) {
        int k = lane * 4;
        float s = p.x * Wout[(k + 0) * 16 + j] + p.y * Wout[(k + 1) * 16 + j] +
                  p.z * Wout[(k + 2) * 16 + j] + p.w * Wout[(k + 3) * 16 + j];
#pragma unroll
        for (int o = 32; o >= 1; o >>= 1) s += __shfl_down(s, o);
        if (lane == 0) logits[j] = s + bout[j];
    }
    __syncthreads();
    if (lane == 0) {
        float m = -INFINITY;
        for (int j = 0; j < 16; ++j) m = fmaxf(m, logits[j]);
        float S = 0.f;
        for (int j = 0; j < 16; ++j) S += expf(logits[j] - m);
        float lse = m + logf(S);
        for (int j = 0; j < 16; ++j) out[g * 16 + j] = logits[j] - lse;
    }
}

// ---------------- launch ----------------

extern "C" void kernel_launch(void* const* d_in, const int* in_sizes, int n_in,
                              void* d_out, int out_size, void* d_ws, size_t ws_size,
                              hipStream_t stream) {
    const float* x     = (const float*)d_in[0];
    const int*   eidx  = (const int*)d_in[1];
    const int*   batch = (const int*)d_in[2];
    const float* W0    = (const float*)d_in[3];
    const float* b0    = (const float*)d_in[4];
    const float* attnW = (const float*)d_in[5];
    const float* attnB = (const float*)d_in[6];
    const float* hw    = (const float*)d_in[7];
    const float* W1    = (const float*)d_in[8];
    const float* b1    = (const float*)d_in[9];
    const float* W2    = (const float*)d_in[10];
    const float* b2    = (const float*)d_in[11];
    const float* Wout  = (const float*)d_in[12];
    const float* bout  = (const float*)d_in[13];
    float* out = (float*)d_out;

    const int N  = in_sizes[0] / 256;
    const int E  = in_sizes[1] / 2;
    const int NG = 512;

    const int* src = eidx;
    const int* dst = eidx + E;

    // workspace layout (floats)
    float* wsf    = (float*)d_ws;
    size_t off    = 0;
    float* bufA   = wsf + off; off += (size_t)N * 256;   // hpre0 -> h1 -> agg2
    float* bufB   = wsf + off; off += (size_t)N * 256;   // agg0  -> hpre2
    float* dis    = wsf + off; off += N;                 // deg -> dis (in place)
    float* tbuf   = wsf + off; off += N;
    float* dvec   = wsf + off; off += N;
    float* zbuf   = wsf + off; off += N;
    float* zagg   = wsf + off; off += N;
    float* pooled = wsf + off; off += (size_t)NG * 256;
    float* cnt    = wsf + off; off += NG;
    float* part1  = wsf + off; off += 256;
    float* part2  = wsf + off; off += 256;
    float* Msc    = wsf + off; off += 1;
    float* Ssc    = wsf + off; off += 1;

    const int TB = 256;
    dim3 blk(TB);

    // zero pooled + cnt (contiguous)
    hipMemsetAsync(pooled, 0, ((size_t)NG * 256 + NG) * sizeof(float), stream);

    // degree (with self loop) -> dis
    k_fill<<<dim3((N + TB - 1) / TB), blk, 0, stream>>>(dis, 1.0f, N);
    k_deg<<<dim3((E + TB - 1) / TB), blk, 0, stream>>>(dst, dis, E);
    k_rsqrt_inplace<<<dim3((N + TB - 1) / TB), blk, 0, stream>>>(dis, N);

    // layer 0: hpre0 = x @ W0
    k_gemm256<<<dim3((N + 63) / 64, 4), blk, 0, stream>>>(x, W0, bufA, N);
    // agg0 = hpre0 * self_norm ; += edges
    k_scale_rows<<<dim3((N * 64 + TB - 1) / TB), blk, 0, stream>>>(bufA, dis, bufB, N);
    k_edge_agg<<<dim3((E * 64 + TB - 1) / TB), blk, 0, stream>>>(src, dst, dis, bufA, bufB, E);
    // t_i, d_i (h0 not materialized)
    k_postact0<<<dim3((N * 64 + TB - 1) / TB), blk, 0, stream>>>(bufB, b0, attnW, attnB, hw,
                                                                tbuf, dvec, N);
    // softmax over N
    k_max1<<<dim3(256), blk, 0, stream>>>(tbuf, part1, N);
    k_max2<<<dim3(1), blk, 0, stream>>>(part1, Msc);
    k_sum1<<<dim3(256), blk, 0, stream>>>(tbuf, Msc, part2, N);
    k_sum2<<<dim3(1), blk, 0, stream>>>(part2, Ssc);
    k_z<<<dim3((N + TB - 1) / TB), blk, 0, stream>>>(tbuf, dvec, dis, Msc, Ssc, zbuf, zagg, N);

    // layer 1 (rank-1): scalar aggregation then broadcast
    k_edge_scalar<<<dim3((E + TB - 1) / TB), blk, 0, stream>>>(src, dst, dis, zbuf, zagg, E);
    k_h1<<<dim3((N * 64 + TB - 1) / TB), blk, 0, stream>>>(zagg, W1, b1, bufA, N);

    // layer 2: hpre2 = h1 @ W2
    k_gemm256<<<dim3((N + 63) / 64, 4), blk, 0, stream>>>(bufA, W2, bufB, N);
    k_scale_rows<<<dim3((N * 64 + TB - 1) / TB), blk, 0, stream>>>(bufB, dis, bufA, N);
    k_edge_agg<<<dim3((E * 64 + TB - 1) / TB), blk, 0, stream>>>(src, dst, dis, bufB, bufA, E);

    // relu+bias+pool, then per-graph head
    k_pool<<<dim3((N * 64 + TB - 1) / TB), blk, 0, stream>>>(bufA, b2, batch, pooled, cnt, N);
    k_final<<<dim3(NG), dim3(64), 0, stream>>>(pooled, cnt, Wout, bout, out, NG);
}

// Round 2
// 796.749 us; speedup vs baseline: 7.3811x; 7.3811x over previous
//
#include <hip/hip_runtime.h>
#include <hip/hip_bf16.h>
#include <math.h>

// ---------------- small utility kernels ----------------

__global__ void k_degi(const int* __restrict__ dst, int* __restrict__ cnt, int E) {
    int i = blockIdx.x * 256 + threadIdx.x;
    if (i < E) atomicAdd(&cnt[dst[i]], 1);
}

__global__ void k_dis(const int* __restrict__ cnt, float* __restrict__ dis, int n) {
    int i = blockIdx.x * 256 + threadIdx.x;
    if (i < n) dis[i] = rsqrtf((float)cnt[i] + 1.0f);
}

// single-block exclusive scan of cnt[0..n) -> rowptr[0..n], rowptr[n]=total
__global__ __launch_bounds__(1024) void k_scan(const int* __restrict__ cnt,
                                               int* __restrict__ rowptr, int n) {
    __shared__ int sm[1024];
    __shared__ int carry;
    const int tid = threadIdx.x;
    if (tid == 0) carry = 0;
    __syncthreads();
    for (int base = 0; base < n; base += 1024) {
        int i = base + tid;
        int v = (i < n) ? cnt[i] : 0;
        sm[tid] = v;
        __syncthreads();
#pragma unroll
        for (int o = 1; o < 1024; o <<= 1) {
            int t = (tid >= o) ? sm[tid - o] : 0;
            __syncthreads();
            sm[tid] += t;
            __syncthreads();
        }
        if (i < n) rowptr[i] = carry + sm[tid] - v;
        __syncthreads();
        if (tid == 0) carry += sm[1023];
        __syncthreads();
    }
    if (tid == 0) rowptr[n] = carry;
}

// scatter edges into CSR (order within a row nondeterministic; sums stay in-threshold)
__global__ void k_fillcsr(const int* __restrict__ src, const int* __restrict__ dst,
                          const float* __restrict__ dis, const int* __restrict__ rowptr,
                          int* __restrict__ fill, int* __restrict__ csrc,
                          float* __restrict__ cw, int E) {
    int e = blockIdx.x * 256 + threadIdx.x;
    if (e >= E) return;
    int d = dst[e], s = src[e];
    int p = rowptr[d] + atomicAdd(&fill[d], 1);
    csrc[p] = s;
    cw[p] = dis[s] * dis[d];
}

// ---------------- fp32 GEMM: C[M,256] = A[M,256] @ B[256,256] ----------------

__global__ __launch_bounds__(256) void k_gemm256(const float* __restrict__ A,
                                                 const float* __restrict__ B,
                                                 float* __restrict__ C, int M) {
    __shared__ float As[16][68];
    __shared__ float Bs[16][68];
    const int bm = blockIdx.x;
    const int bn = blockIdx.y;          // 0..3
    const int t  = threadIdx.x;
    const int ty = t >> 4, tx = t & 15;
    const int row0 = bm * 64;

    const int ar = t >> 2;
    const int ac = (t & 3) * 4;
    const int br = t >> 4;
    const int bc = (t & 15) * 4;

    float acc[4][4] = {};

    for (int k0 = 0; k0 < 256; k0 += 16) {
        float4 av = make_float4(0.f, 0.f, 0.f, 0.f);
        int arow = row0 + ar;
        if (arow < M) av = *(const float4*)(A + (size_t)arow * 256 + k0 + ac);
        As[ac + 0][ar] = av.x;
        As[ac + 1][ar] = av.y;
        As[ac + 2][ar] = av.z;
        As[ac + 3][ar] = av.w;

        float4 bv = *(const float4*)(B + (size_t)(k0 + br) * 256 + bn * 64 + bc);
        *(float4*)(&Bs[br][bc]) = bv;

        __syncthreads();
#pragma unroll
        for (int k = 0; k < 16; ++k) {
            float a[4], b[4];
#pragma unroll
            for (int i = 0; i < 4; ++i) a[i] = As[k][ty * 4 + i];
#pragma unroll
            for (int j = 0; j < 4; ++j) b[j] = Bs[k][tx * 4 + j];
#pragma unroll
            for (int i = 0; i < 4; ++i)
#pragma unroll
                for (int j = 0; j < 4; ++j) acc[i][j] += a[i] * b[j];
        }
        __syncthreads();
    }

#pragma unroll
    for (int i = 0; i < 4; ++i) {
        int r = row0 + ty * 4 + i;
        if (r < M) {
            float4 v = make_float4(acc[i][0], acc[i][1], acc[i][2], acc[i][3]);
            *(float4*)(C + (size_t)r * 256 + bn * 64 + tx * 4) = v;
        }
    }
}

// ---------------- layer-0: CSR gather + bias + relu + attn/hyperedge dots ----------------
// one wave per dst row; AGG never materialized

__global__ __launch_bounds__(256) void k_gather0(const float* __restrict__ H,
                                                 const float* __restrict__ dis,
                                                 const int* __restrict__ rowptr,
                                                 const int* __restrict__ csrc,
                                                 const float* __restrict__ cw,
                                                 const float* __restrict__ b0,
                                                 const float* __restrict__ attnW,
                                                 const float* __restrict__ attnB,
                                                 const float* __restrict__ hw,
                                                 float* __restrict__ t,
                                                 float* __restrict__ dvec, int n) {
    int wid  = (blockIdx.x * 256 + threadIdx.x) >> 6;
    int lane = threadIdx.x & 63;
    if (wid >= n) return;
    float di = dis[wid];
    float sn = di * di;
    float4 acc = ((const float4*)(H + (size_t)wid * 256))[lane];
    acc.x *= sn; acc.y *= sn; acc.z *= sn; acc.w *= sn;
    int e1 = rowptr[wid + 1];
    for (int e = rowptr[wid]; e < e1; ++e) {
        int s = csrc[e];
        float w = cw[e];
        float4 v = ((const float4*)(H + (size_t)s * 256))[lane];
        acc.x += v.x * w; acc.y += v.y * w; acc.z += v.z * w; acc.w += v.w * w;
    }
    float4 bb = ((const float4*)b0)[lane];
    acc.x = fmaxf(acc.x + bb.x, 0.f);
    acc.y = fmaxf(acc.y + bb.y, 0.f);
    acc.z = fmaxf(acc.z + bb.z, 0.f);
    acc.w = fmaxf(acc.w + bb.w, 0.f);
    float4 aw = ((const float4*)attnW)[lane];
    float4 hv = ((const float4*)hw)[lane];
    float tp = acc.x * aw.x + acc.y * aw.y + acc.z * aw.z + acc.w * aw.w;
    float dp = acc.x * hv.x + acc.y * hv.y + acc.z * hv.z + acc.w * hv.w;
#pragma unroll
    for (int o = 32; o >= 1; o >>= 1) {
        tp += __shfl_down(tp, o);
        dp += __shfl_down(dp, o);
    }
    if (lane == 0) {
        t[wid]    = tp + attnB[0];
        dvec[wid] = dp;
    }
}

// ---------------- layer-2: CSR gather + bias + relu + mean-pool accumulate ----------------

__global__ __launch_bounds__(256) void k_gather_pool(const float* __restrict__ H,
                                                     const float* __restrict__ dis,
                                                     const int* __restrict__ rowptr,
                                                     const int* __restrict__ csrc,
                                                     const float* __restrict__ cw,
                                                     const float* __restrict__ b2,
                                                     const int* __restrict__ batch,
                                                     float* __restrict__ pooled,
                                                     float* __restrict__ cntg, int n) {
    int wid  = (blockIdx.x * 256 + threadIdx.x) >> 6;
    int lane = threadIdx.x & 63;
    if (wid >= n) return;
    float di = dis[wid];
    float sn = di * di;
    float4 acc = ((const float4*)(H + (size_t)wid * 256))[lane];
    acc.x *= sn; acc.y *= sn; acc.z *= sn; acc.w *= sn;
    int e1 = rowptr[wid + 1];
    for (int e = rowptr[wid]; e < e1; ++e) {
        int s = csrc[e];
        float w = cw[e];
        float4 v = ((const float4*)(H + (size_t)s * 256))[lane];
        acc.x += v.x * w; acc.y += v.y * w; acc.z += v.z * w; acc.w += v.w * w;
    }
    float4 bb = ((const float4*)b2)[lane];
    acc.x = fmaxf(acc.x + bb.x, 0.f);
    acc.y = fmaxf(acc.y + bb.y, 0.f);
    acc.z = fmaxf(acc.z + bb.z, 0.f);
    acc.w = fmaxf(acc.w + bb.w, 0.f);
    int g = batch[wid];
    float* pg = pooled + (size_t)g * 256 + lane * 4;
    atomicAdd(pg + 0, acc.x);
    atomicAdd(pg + 1, acc.y);
    atomicAdd(pg + 2, acc.z);
    atomicAdd(pg + 3, acc.w);
    if (lane == 0) atomicAdd(&cntg[g], 1.0f);
}

// ---------------- global softmax over N ----------------

__global__ __launch_bounds__(256) void k_max1(const float* __restrict__ t,
                                              float* __restrict__ partial, int n) {
    __shared__ float sm[256];
    float m = -INFINITY;
    for (int i = blockIdx.x * 256 + threadIdx.x; i < n; i += 256 * 256)
        m = fmaxf(m, t[i]);
    sm[threadIdx.x] = m;
    __syncthreads();
    for (int s = 128; s > 0; s >>= 1) {
        if (threadIdx.x < s) sm[threadIdx.x] = fmaxf(sm[threadIdx.x], sm[threadIdx.x + s]);
        __syncthreads();
    }
    if (threadIdx.x == 0) partial[blockIdx.x] = sm[0];
}

__global__ __launch_bounds__(256) void k_max2(const float* __restrict__ partial,
                                              float* __restrict__ M) {
    __shared__ float sm[256];
    sm[threadIdx.x] = partial[threadIdx.x];
    __syncthreads();
    for (int s = 128; s > 0; s >>= 1) {
        if (threadIdx.x < s) sm[threadIdx.x] = fmaxf(sm[threadIdx.x], sm[threadIdx.x + s]);
        __syncthreads();
    }
    if (threadIdx.x == 0) *M = sm[0];
}

__global__ __launch_bounds__(256) void k_sum1(const float* __restrict__ t,
                                              const float* __restrict__ M,
                                              float* __restrict__ partial, int n) {
    __shared__ float sm[256];
    float m = *M;
    float s0 = 0.f;
    for (int i = blockIdx.x * 256 + threadIdx.x; i < n; i += 256 * 256)
        s0 += expf(t[i] - m);
    sm[threadIdx.x] = s0;
    __syncthreads();
    for (int s = 128; s > 0; s >>= 1) {
        if (threadIdx.x < s) sm[threadIdx.x] += sm[threadIdx.x + s];
        __syncthreads();
    }
    if (threadIdx.x == 0) partial[blockIdx.x] = sm[0];
}

__global__ __launch_bounds__(256) void k_sum2(const float* __restrict__ partial,
                                              float* __restrict__ S) {
    __shared__ float sm[256];
    sm[threadIdx.x] = partial[threadIdx.x];
    __syncthreads();
    for (int s = 128; s > 0; s >>= 1) {
        if (threadIdx.x < s) sm[threadIdx.x] += sm[threadIdx.x + s];
        __syncthreads();
    }
    if (threadIdx.x == 0) *S = sm[0];
}

// z_i = softmax_i * d_i
__global__ void k_z(const float* __restrict__ t, const float* __restrict__ dvec,
                    const float* __restrict__ M, const float* __restrict__ S,
                    float* __restrict__ z, int n) {
    int i = blockIdx.x * 256 + threadIdx.x;
    if (i >= n) return;
    z[i] = expf(t[i] - *M) / *S * dvec[i];
}

// scalar CSR gather: zagg_i = z_i/deg_i + sum_e z[src]*w
__global__ void k_zgather(const float* __restrict__ z, const float* __restrict__ dis,
                          const int* __restrict__ rowptr, const int* __restrict__ csrc,
                          const float* __restrict__ cw, float* __restrict__ zagg, int n) {
    int i = blockIdx.x * 256 + threadIdx.x;
    if (i >= n) return;
    float di = dis[i];
    float a = z[i] * di * di;
    int e1 = rowptr[i + 1];
    for (int e = rowptr[i]; e < e1; ++e) a += z[csrc[e]] * cw[e];
    zagg[i] = a;
}

// h1[i,j] = relu(zagg[i]*W1[j] + b1[j])
__global__ void k_h1(const float* __restrict__ zagg, const float* __restrict__ W1,
                     const float* __restrict__ b1, float* __restrict__ H1, int n) {
    int idx = blockIdx.x * 256 + threadIdx.x;
    int total = n * 64;
    if (idx >= total) return;
    int row = idx >> 6, lane = idx & 63;
    float s = zagg[row];
    float4 w  = ((const float4*)W1)[lane];
    float4 bb = ((const float4*)b1)[lane];
    float4 v;
    v.x = fmaxf(s * w.x + bb.x, 0.f);
    v.y = fmaxf(s * w.y + bb.y, 0.f);
    v.z = fmaxf(s * w.z + bb.z, 0.f);
    v.w = fmaxf(s * w.w + bb.w, 0.f);
    ((float4*)H1)[idx] = v;
}

// per-graph head
__global__ __launch_bounds__(64) void k_final(const float* __restrict__ pooled,
                                              const float* __restrict__ cntg,
                                              const float* __restrict__ Wout,
                                              const float* __restrict__ bout,
                                              float* __restrict__ out, int ngraphs) {
    int g = blockIdx.x;
    if (g >= ngraphs) return;
    int lane = threadIdx.x;
    float inv = 1.0f / fmaxf(cntg[g], 1.0f);
    float4 p = ((const float4*)(pooled + (size_t)g * 256))[lane];
    p.x *= inv; p.y *= inv; p.z *= inv; p.w *= inv;
    __shared__ float logits[16];
    for (int j = 0; j < 16; ++j) {
        int k = lane * 4;
        float s = p.x * Wout[(k + 0) * 16 + j] + p.y * Wout[(k + 1) * 16 + j] +
                  p.z * Wout[(k + 2) * 16 + j] + p.w * Wout[(k + 3) * 16 + j];
#pragma unroll
        for (int o = 32; o >= 1; o >>= 1) s += __shfl_down(s, o);
        if (lane == 0) logits[j] = s + bout[j];
    }
    __syncthreads();
    if (lane == 0) {
        float m = -INFINITY;
        for (int j = 0; j < 16; ++j) m = fmaxf(m, logits[j]);
        float S = 0.f;
        for (int j = 0; j < 16; ++j) S += expf(logits[j] - m);
        float lse = m + logf(S);
        for (int j = 0; j < 16; ++j) out[g * 16 + j] = logits[j] - lse;
    }
}

// ---------------- launch ----------------

extern "C" void kernel_launch(void* const* d_in, const int* in_sizes, int n_in,
                              void* d_out, int out_size, void* d_ws, size_t ws_size,
                              hipStream_t stream) {
    const float* x     = (const float*)d_in[0];
    const int*   eidx  = (const int*)d_in[1];
    const int*   batch = (const int*)d_in[2];
    const float* W0    = (const float*)d_in[3];
    const float* b0    = (const float*)d_in[4];
    const float* attnW = (const float*)d_in[5];
    const float* attnB = (const float*)d_in[6];
    const float* hw    = (const float*)d_in[7];
    const float* W1    = (const float*)d_in[8];
    const float* b1    = (const float*)d_in[9];
    const float* W2    = (const float*)d_in[10];
    const float* b2    = (const float*)d_in[11];
    const float* Wout  = (const float*)d_in[12];
    const float* bout  = (const float*)d_in[13];
    float* out = (float*)d_out;

    const int N  = in_sizes[0] / 256;
    const int E  = in_sizes[1] / 2;
    const int NG = 512;

    const int* src = eidx;
    const int* dst = eidx + E;

    // workspace layout (4-byte elements, each region 16B-aligned)
    float* wsf = (float*)d_ws;
    size_t off = 0;
    auto alloc = [&](size_t n) { size_t o = off; off = (off + n + 15) & ~(size_t)15; return o; };
    float* bufA   = wsf + alloc((size_t)N * 256);   // hpre0 -> h1
    float* bufB   = wsf + alloc((size_t)N * 256);   // hpre2
    float* dis    = wsf + alloc(N);
    float* tbuf   = wsf + alloc(N);
    float* dvec   = wsf + alloc(N);
    float* zbuf   = wsf + alloc(N);
    float* zagg   = wsf + alloc(N);
    int*   rowptr = (int*)(wsf + alloc(N + 1));
    int*   csrc   = (int*)(wsf + alloc(E));
    float* cw     = wsf + alloc(E);
    float* part1  = wsf + alloc(256);
    float* part2  = wsf + alloc(256);
    float* Msc    = wsf + alloc(16);
    float* Ssc    = wsf + alloc(16);
    // zero region: cnti[N], fill[N], pooled[NG*256], cntg[NG]  (contiguous)
    size_t zoff   = off;
    int*   cnti   = (int*)(wsf + alloc(N));
    int*   fill   = (int*)(wsf + alloc(N));
    float* pooled = wsf + alloc((size_t)NG * 256);
    float* cntg   = wsf + alloc(NG);
    size_t zbytes = (off - zoff) * sizeof(float);

    const int TB = 256;
    dim3 blk(TB);

    hipMemsetAsync(wsf + zoff, 0, zbytes, stream);

    // CSR build
    k_degi<<<dim3((E + TB - 1) / TB), blk, 0, stream>>>(dst, cnti, E);
    k_scan<<<dim3(1), dim3(1024), 0, stream>>>(cnti, rowptr, N);
    k_dis<<<dim3((N + TB - 1) / TB), blk, 0, stream>>>(cnti, dis, N);
    k_fillcsr<<<dim3((E + TB - 1) / TB), blk, 0, stream>>>(src, dst, dis, rowptr, fill, csrc, cw, E);

    // layer 0
    k_gemm256<<<dim3((N + 63) / 64, 4), blk, 0, stream>>>(x, W0, bufA, N);
    k_gather0<<<dim3((N * 64 + TB - 1) / TB), blk, 0, stream>>>(bufA, dis, rowptr, csrc, cw,
                                                                b0, attnW, attnB, hw,
                                                                tbuf, dvec, N);
    // softmax over N
    k_max1<<<dim3(256), blk, 0, stream>>>(tbuf, part1, N);
    k_max2<<<dim3(1), blk, 0, stream>>>(part1, Msc);
    k_sum1<<<dim3(256), blk, 0, stream>>>(tbuf, Msc, part2, N);
    k_sum2<<<dim3(1), blk, 0, stream>>>(part2, Ssc);
    k_z<<<dim3((N + TB - 1) / TB), blk, 0, stream>>>(tbuf, dvec, Msc, Ssc, zbuf, N);

    // layer 1 (rank-1): scalar CSR gather then broadcast
    k_zgather<<<dim3((N + TB - 1) / TB), blk, 0, stream>>>(zbuf, dis, rowptr, csrc, cw, zagg, N);
    k_h1<<<dim3((N * 64 + TB - 1) / TB), blk, 0, stream>>>(zagg, W1, b1, bufA, N);

    // layer 2
    k_gemm256<<<dim3((N + 63) / 64, 4), blk, 0, stream>>>(bufA, W2, bufB, N);
    k_gather_pool<<<dim3((N * 64 + TB - 1) / TB), blk, 0, stream>>>(bufB, dis, rowptr, csrc, cw,
                                                                    b2, batch, pooled, cntg, N);
    k_final<<<dim3(NG), dim3(64), 0, stream>>>(pooled, cntg, Wout, bout, out, NG);
}

// Round 3
// 709.357 us; speedup vs baseline: 8.2904x; 1.1232x over previous
//
#include <hip/hip_runtime.h>
#include <hip/hip_bf16.h>
#include <math.h>

// ---------------- helpers ----------------

__device__ __forceinline__ unsigned short f2bf(float f) {
    unsigned x = __float_as_uint(f);
    unsigned r = (x + 0x7fff + ((x >> 16) & 1)) >> 16;   // round-to-nearest-even
    return (unsigned short)r;
}

__device__ __forceinline__ float bf2f(unsigned short u) {
    return __uint_as_float((unsigned)u << 16);
}

// ---------------- small utility kernels ----------------

__global__ void k_degi(const int* __restrict__ dst, int* __restrict__ cnt, int E) {
    int i = blockIdx.x * 256 + threadIdx.x;
    if (i < E) atomicAdd(&cnt[dst[i]], 1);
}

__global__ void k_dis(const int* __restrict__ cnt, float* __restrict__ dis, int n) {
    int i = blockIdx.x * 256 + threadIdx.x;
    if (i < n) dis[i] = rsqrtf((float)cnt[i] + 1.0f);
}

// single-block exclusive scan of cnt[0..n) -> rowptr[0..n], rowptr[n]=total
__global__ __launch_bounds__(1024) void k_scan(const int* __restrict__ cnt,
                                               int* __restrict__ rowptr, int n) {
    __shared__ int sm[1024];
    __shared__ int carry;
    const int tid = threadIdx.x;
    if (tid == 0) carry = 0;
    __syncthreads();
    for (int base = 0; base < n; base += 1024) {
        int i = base + tid;
        int v = (i < n) ? cnt[i] : 0;
        sm[tid] = v;
        __syncthreads();
#pragma unroll
        for (int o = 1; o < 1024; o <<= 1) {
            int t = (tid >= o) ? sm[tid - o] : 0;
            __syncthreads();
            sm[tid] += t;
            __syncthreads();
        }
        if (i < n) rowptr[i] = carry + sm[tid] - v;
        __syncthreads();
        if (tid == 0) carry += sm[1023];
        __syncthreads();
    }
    if (tid == 0) rowptr[n] = carry;
}

__global__ void k_fillcsr(const int* __restrict__ src, const int* __restrict__ dst,
                          const float* __restrict__ dis, const int* __restrict__ rowptr,
                          int* __restrict__ fill, int* __restrict__ csrc,
                          float* __restrict__ cw, int E) {
    int e = blockIdx.x * 256 + threadIdx.x;
    if (e >= E) return;
    int d = dst[e], s = src[e];
    int p = rowptr[d] + atomicAdd(&fill[d], 1);
    csrc[p] = s;
    cw[p] = dis[s] * dis[d];
}

// ---------------- fp32 GEMM, bf16 output: C[M,256] = A[M,256] @ B[256,256] ----------------

__global__ __launch_bounds__(256) void k_gemm256(const float* __restrict__ A,
                                                 const float* __restrict__ B,
                                                 unsigned short* __restrict__ C, int M) {
    __shared__ float As[16][68];
    __shared__ float Bs[16][68];
    const int bm = blockIdx.x;
    const int bn = blockIdx.y;          // 0..3
    const int t  = threadIdx.x;
    const int ty = t >> 4, tx = t & 15;
    const int row0 = bm * 64;

    const int ar = t >> 2;
    const int ac = (t & 3) * 4;
    const int br = t >> 4;
    const int bc = (t & 15) * 4;

    float acc[4][4] = {};

    for (int k0 = 0; k0 < 256; k0 += 16) {
        float4 av = make_float4(0.f, 0.f, 0.f, 0.f);
        int arow = row0 + ar;
        if (arow < M) av = *(const float4*)(A + (size_t)arow * 256 + k0 + ac);
        As[ac + 0][ar] = av.x;
        As[ac + 1][ar] = av.y;
        As[ac + 2][ar] = av.z;
        As[ac + 3][ar] = av.w;

        float4 bv = *(const float4*)(B + (size_t)(k0 + br) * 256 + bn * 64 + bc);
        *(float4*)(&Bs[br][bc]) = bv;

        __syncthreads();
#pragma unroll
        for (int k = 0; k < 16; ++k) {
            float a[4], b[4];
#pragma unroll
            for (int i = 0; i < 4; ++i) a[i] = As[k][ty * 4 + i];
#pragma unroll
            for (int j = 0; j < 4; ++j) b[j] = Bs[k][tx * 4 + j];
#pragma unroll
            for (int i = 0; i < 4; ++i)
#pragma unroll
                for (int j = 0; j < 4; ++j) acc[i][j] += a[i] * b[j];
        }
        __syncthreads();
    }

#pragma unroll
    for (int i = 0; i < 4; ++i) {
        int r = row0 + ty * 4 + i;
        if (r < M) {
            ushort4 o;
            o.x = f2bf(acc[i][0]);
            o.y = f2bf(acc[i][1]);
            o.z = f2bf(acc[i][2]);
            o.w = f2bf(acc[i][3]);
            *(ushort4*)(C + (size_t)r * 256 + bn * 64 + tx * 4) = o;
        }
    }
}

// ---------------- CSR gather cores (bf16 H, 4-way edge unroll) ----------------

__device__ __forceinline__ void bf_fma(float4& acc, ushort4 u, float w) {
    acc.x += bf2f(u.x) * w;
    acc.y += bf2f(u.y) * w;
    acc.z += bf2f(u.z) * w;
    acc.w += bf2f(u.w) * w;
}

// layer-0: gather + bias + relu + attn/hyperedge dots (AGG never materialized)
__global__ __launch_bounds__(256) void k_gather0(const unsigned short* __restrict__ H,
                                                 const float* __restrict__ dis,
                                                 const int* __restrict__ rowptr,
                                                 const int* __restrict__ csrc,
                                                 const float* __restrict__ cw,
                                                 const float* __restrict__ b0,
                                                 const float* __restrict__ attnW,
                                                 const float* __restrict__ attnB,
                                                 const float* __restrict__ hw,
                                                 float* __restrict__ t,
                                                 float* __restrict__ dvec, int n) {
    int wid  = (blockIdx.x * 256 + threadIdx.x) >> 6;
    int lane = threadIdx.x & 63;
    if (wid >= n) return;
    float di = dis[wid];
    float sn = di * di;
    ushort4 us = ((const ushort4*)(H + (size_t)wid * 256))[lane];
    float4 acc = make_float4(bf2f(us.x) * sn, bf2f(us.y) * sn, bf2f(us.z) * sn, bf2f(us.w) * sn);
    int e  = rowptr[wid];
    int e1 = rowptr[wid + 1];
    for (; e + 4 <= e1; e += 4) {
        int s0 = csrc[e], s1 = csrc[e + 1], s2 = csrc[e + 2], s3 = csrc[e + 3];
        float w0 = cw[e], w1 = cw[e + 1], w2 = cw[e + 2], w3 = cw[e + 3];
        ushort4 u0 = ((const ushort4*)(H + (size_t)s0 * 256))[lane];
        ushort4 u1 = ((const ushort4*)(H + (size_t)s1 * 256))[lane];
        ushort4 u2 = ((const ushort4*)(H + (size_t)s2 * 256))[lane];
        ushort4 u3 = ((const ushort4*)(H + (size_t)s3 * 256))[lane];
        bf_fma(acc, u0, w0);
        bf_fma(acc, u1, w1);
        bf_fma(acc, u2, w2);
        bf_fma(acc, u3, w3);
    }
    for (; e < e1; ++e) {
        int s = csrc[e];
        float w = cw[e];
        ushort4 u = ((const ushort4*)(H + (size_t)s * 256))[lane];
        bf_fma(acc, u, w);
    }
    float4 bb = ((const float4*)b0)[lane];
    acc.x = fmaxf(acc.x + bb.x, 0.f);
    acc.y = fmaxf(acc.y + bb.y, 0.f);
    acc.z = fmaxf(acc.z + bb.z, 0.f);
    acc.w = fmaxf(acc.w + bb.w, 0.f);
    float4 aw = ((const float4*)attnW)[lane];
    float4 hv = ((const float4*)hw)[lane];
    float tp = acc.x * aw.x + acc.y * aw.y + acc.z * aw.z + acc.w * aw.w;
    float dp = acc.x * hv.x + acc.y * hv.y + acc.z * hv.z + acc.w * hv.w;
#pragma unroll
    for (int o = 32; o >= 1; o >>= 1) {
        tp += __shfl_down(tp, o);
        dp += __shfl_down(dp, o);
    }
    if (lane == 0) {
        t[wid]    = tp + attnB[0];
        dvec[wid] = dp;
    }
}

// layer-2: gather + bias + relu + mean-pool accumulate
__global__ __launch_bounds__(256) void k_gather_pool(const unsigned short* __restrict__ H,
                                                     const float* __restrict__ dis,
                                                     const int* __restrict__ rowptr,
                                                     const int* __restrict__ csrc,
                                                     const float* __restrict__ cw,
                                                     const float* __restrict__ b2,
                                                     const int* __restrict__ batch,
                                                     float* __restrict__ pooled,
                                                     float* __restrict__ cntg, int n) {
    int wid  = (blockIdx.x * 256 + threadIdx.x) >> 6;
    int lane = threadIdx.x & 63;
    if (wid >= n) return;
    float di = dis[wid];
    float sn = di * di;
    ushort4 us = ((const ushort4*)(H + (size_t)wid * 256))[lane];
    float4 acc = make_float4(bf2f(us.x) * sn, bf2f(us.y) * sn, bf2f(us.z) * sn, bf2f(us.w) * sn);
    int e  = rowptr[wid];
    int e1 = rowptr[wid + 1];
    for (; e + 4 <= e1; e += 4) {
        int s0 = csrc[e], s1 = csrc[e + 1], s2 = csrc[e + 2], s3 = csrc[e + 3];
        float w0 = cw[e], w1 = cw[e + 1], w2 = cw[e + 2], w3 = cw[e + 3];
        ushort4 u0 = ((const ushort4*)(H + (size_t)s0 * 256))[lane];
        ushort4 u1 = ((const ushort4*)(H + (size_t)s1 * 256))[lane];
        ushort4 u2 = ((const ushort4*)(H + (size_t)s2 * 256))[lane];
        ushort4 u3 = ((const ushort4*)(H + (size_t)s3 * 256))[lane];
        bf_fma(acc, u0, w0);
        bf_fma(acc, u1, w1);
        bf_fma(acc, u2, w2);
        bf_fma(acc, u3, w3);
    }
    for (; e < e1; ++e) {
        int s = csrc[e];
        float w = cw[e];
        ushort4 u = ((const ushort4*)(H + (size_t)s * 256))[lane];
        bf_fma(acc, u, w);
    }
    float4 bb = ((const float4*)b2)[lane];
    acc.x = fmaxf(acc.x + bb.x, 0.f);
    acc.y = fmaxf(acc.y + bb.y, 0.f);
    acc.z = fmaxf(acc.z + bb.z, 0.f);
    acc.w = fmaxf(acc.w + bb.w, 0.f);
    int g = batch[wid];
    float* pg = pooled + (size_t)g * 256 + lane * 4;
    atomicAdd(pg + 0, acc.x);
    atomicAdd(pg + 1, acc.y);
    atomicAdd(pg + 2, acc.z);
    atomicAdd(pg + 3, acc.w);
    if (lane == 0) atomicAdd(&cntg[g], 1.0f);
}

// ---------------- global softmax over N ----------------

__global__ __launch_bounds__(256) void k_max1(const float* __restrict__ t,
                                              float* __restrict__ partial, int n) {
    __shared__ float sm[256];
    float m = -INFINITY;
    for (int i = blockIdx.x * 256 + threadIdx.x; i < n; i += 256 * 256)
        m = fmaxf(m, t[i]);
    sm[threadIdx.x] = m;
    __syncthreads();
    for (int s = 128; s > 0; s >>= 1) {
        if (threadIdx.x < s) sm[threadIdx.x] = fmaxf(sm[threadIdx.x], sm[threadIdx.x + s]);
        __syncthreads();
    }
    if (threadIdx.x == 0) partial[blockIdx.x] = sm[0];
}

__global__ __launch_bounds__(256) void k_max2(const float* __restrict__ partial,
                                              float* __restrict__ M) {
    __shared__ float sm[256];
    sm[threadIdx.x] = partial[threadIdx.x];
    __syncthreads();
    for (int s = 128; s > 0; s >>= 1) {
        if (threadIdx.x < s) sm[threadIdx.x] = fmaxf(sm[threadIdx.x], sm[threadIdx.x + s]);
        __syncthreads();
    }
    if (threadIdx.x == 0) *M = sm[0];
}

__global__ __launch_bounds__(256) void k_sum1(const float* __restrict__ t,
                                              const float* __restrict__ M,
                                              float* __restrict__ partial, int n) {
    __shared__ float sm[256];
    float m = *M;
    float s0 = 0.f;
    for (int i = blockIdx.x * 256 + threadIdx.x; i < n; i += 256 * 256)
        s0 += expf(t[i] - m);
    sm[threadIdx.x] = s0;
    __syncthreads();
    for (int s = 128; s > 0; s >>= 1) {
        if (threadIdx.x < s) sm[threadIdx.x] += sm[threadIdx.x + s];
        __syncthreads();
    }
    if (threadIdx.x == 0) partial[blockIdx.x] = sm[0];
}

__global__ __launch_bounds__(256) void k_sum2(const float* __restrict__ partial,
                                              float* __restrict__ S) {
    __shared__ float sm[256];
    sm[threadIdx.x] = partial[threadIdx.x];
    __syncthreads();
    for (int s = 128; s > 0; s >>= 1) {
        if (threadIdx.x < s) sm[threadIdx.x] += sm[threadIdx.x + s];
        __syncthreads();
    }
    if (threadIdx.x == 0) *S = sm[0];
}

__global__ void k_z(const float* __restrict__ t, const float* __restrict__ dvec,
                    const float* __restrict__ M, const float* __restrict__ S,
                    float* __restrict__ z, int n) {
    int i = blockIdx.x * 256 + threadIdx.x;
    if (i >= n) return;
    z[i] = expf(t[i] - *M) / *S * dvec[i];
}

// scalar CSR gather: zagg_i = z_i/deg_i + sum_e z[src]*w
__global__ void k_zgather(const float* __restrict__ z, const float* __restrict__ dis,
                          const int* __restrict__ rowptr, const int* __restrict__ csrc,
                          const float* __restrict__ cw, float* __restrict__ zagg, int n) {
    int i = blockIdx.x * 256 + threadIdx.x;
    if (i >= n) return;
    float di = dis[i];
    float a = z[i] * di * di;
    int e1 = rowptr[i + 1];
    for (int e = rowptr[i]; e < e1; ++e) a += z[csrc[e]] * cw[e];
    zagg[i] = a;
}

// h1[i,j] = relu(zagg[i]*W1[j] + b1[j])  (fp32 out, feeds GEMM2)
__global__ void k_h1(const float* __restrict__ zagg, const float* __restrict__ W1,
                     const float* __restrict__ b1, float* __restrict__ H1, int n) {
    int idx = blockIdx.x * 256 + threadIdx.x;
    int total = n * 64;
    if (idx >= total) return;
    int row = idx >> 6, lane = idx & 63;
    float s = zagg[row];
    float4 w  = ((const float4*)W1)[lane];
    float4 bb = ((const float4*)b1)[lane];
    float4 v;
    v.x = fmaxf(s * w.x + bb.x, 0.f);
    v.y = fmaxf(s * w.y + bb.y, 0.f);
    v.z = fmaxf(s * w.z + bb.z, 0.f);
    v.w = fmaxf(s * w.w + bb.w, 0.f);
    ((float4*)H1)[idx] = v;
}

// per-graph head
__global__ __launch_bounds__(64) void k_final(const float* __restrict__ pooled,
                                              const float* __restrict__ cntg,
                                              const float* __restrict__ Wout,
                                              const float* __restrict__ bout,
                                              float* __restrict__ out, int ngraphs) {
    int g = blockIdx.x;
    if (g >= ngraphs) return;
    int lane = threadIdx.x;
    float inv = 1.0f / fmaxf(cntg[g], 1.0f);
    float4 p = ((const float4*)(pooled + (size_t)g * 256))[lane];
    p.x *= inv; p.y *= inv; p.z *= inv; p.w *= inv;
    __shared__ float logits[16];
    for (int j = 0; j < 16; ++j) {
        int k = lane * 4;
        float s = p.x * Wout[(k + 0) * 16 + j] + p.y * Wout[(k + 1) * 16 + j] +
                  p.z * Wout[(k + 2) * 16 + j] + p.w * Wout[(k + 3) * 16 + j];
#pragma unroll
        for (int o = 32; o >= 1; o >>= 1) s += __shfl_down(s, o);
        if (lane == 0) logits[j] = s + bout[j];
    }
    __syncthreads();
    if (lane == 0) {
        float m = -INFINITY;
        for (int j = 0; j < 16; ++j) m = fmaxf(m, logits[j]);
        float S = 0.f;
        for (int j = 0; j < 16; ++j) S += expf(logits[j] - m);
        float lse = m + logf(S);
        for (int j = 0; j < 16; ++j) out[g * 16 + j] = logits[j] - lse;
    }
}

// ---------------- launch ----------------

extern "C" void kernel_launch(void* const* d_in, const int* in_sizes, int n_in,
                              void* d_out, int out_size, void* d_ws, size_t ws_size,
                              hipStream_t stream) {
    const float* x     = (const float*)d_in[0];
    const int*   eidx  = (const int*)d_in[1];
    const int*   batch = (const int*)d_in[2];
    const float* W0    = (const float*)d_in[3];
    const float* b0    = (const float*)d_in[4];
    const float* attnW = (const float*)d_in[5];
    const float* attnB = (const float*)d_in[6];
    const float* hw    = (const float*)d_in[7];
    const float* W1    = (const float*)d_in[8];
    const float* b1    = (const float*)d_in[9];
    const float* W2    = (const float*)d_in[10];
    const float* b2    = (const float*)d_in[11];
    const float* Wout  = (const float*)d_in[12];
    const float* bout  = (const float*)d_in[13];
    float* out = (float*)d_out;

    const int N  = in_sizes[0] / 256;
    const int E  = in_sizes[1] / 2;
    const int NG = 512;

    const int* src = eidx;
    const int* dst = eidx + E;

    // workspace layout (4-byte elements, each region 16B-aligned)
    float* wsf = (float*)d_ws;
    size_t off = 0;
    auto alloc = [&](size_t n) { size_t o = off; off = (off + n + 15) & ~(size_t)15; return o; };
    float*          bufA   = wsf + alloc((size_t)N * 256);   // h1 (fp32)
    unsigned short* bufHb  = (unsigned short*)(wsf + alloc((size_t)N * 128)); // hpre0/hpre2 bf16
    float* dis    = wsf + alloc(N);
    float* tbuf   = wsf + alloc(N);
    float* dvec   = wsf + alloc(N);
    float* zbuf   = wsf + alloc(N);
    float* zagg   = wsf + alloc(N);
    int*   rowptr = (int*)(wsf + alloc(N + 1));
    int*   csrc   = (int*)(wsf + alloc(E));
    float* cw     = wsf + alloc(E);
    float* part1  = wsf + alloc(256);
    float* part2  = wsf + alloc(256);
    float* Msc    = wsf + alloc(16);
    float* Ssc    = wsf + alloc(16);
    // zero region: cnti[N], fill[N], pooled[NG*256], cntg[NG]  (contiguous)
    size_t zoff   = off;
    int*   cnti   = (int*)(wsf + alloc(N));
    int*   fill   = (int*)(wsf + alloc(N));
    float* pooled = wsf + alloc((size_t)NG * 256);
    float* cntg   = wsf + alloc(NG);
    size_t zbytes = (off - zoff) * sizeof(float);

    const int TB = 256;
    dim3 blk(TB);

    hipMemsetAsync(wsf + zoff, 0, zbytes, stream);

    // CSR build
    k_degi<<<dim3((E + TB - 1) / TB), blk, 0, stream>>>(dst, cnti, E);
    k_scan<<<dim3(1), dim3(1024), 0, stream>>>(cnti, rowptr, N);
    k_dis<<<dim3((N + TB - 1) / TB), blk, 0, stream>>>(cnti, dis, N);
    k_fillcsr<<<dim3((E + TB - 1) / TB), blk, 0, stream>>>(src, dst, dis, rowptr, fill, csrc, cw, E);

    // layer 0
    k_gemm256<<<dim3((N + 63) / 64, 4), blk, 0, stream>>>(x, W0, bufHb, N);
    k_gather0<<<dim3((N * 64 + TB - 1) / TB), blk, 0, stream>>>(bufHb, dis, rowptr, csrc, cw,
                                                                b0, attnW, attnB, hw,
                                                                tbuf, dvec, N);
    // softmax over N
    k_max1<<<dim3(256), blk, 0, stream>>>(tbuf, part1, N);
    k_max2<<<dim3(1), blk, 0, stream>>>(part1, Msc);
    k_sum1<<<dim3(256), blk, 0, stream>>>(tbuf, Msc, part2, N);
    k_sum2<<<dim3(1), blk, 0, stream>>>(part2, Ssc);
    k_z<<<dim3((N + TB - 1) / TB), blk, 0, stream>>>(tbuf, dvec, Msc, Ssc, zbuf, N);

    // layer 1 (rank-1): scalar CSR gather then broadcast
    k_zgather<<<dim3((N + TB - 1) / TB), blk, 0, stream>>>(zbuf, dis, rowptr, csrc, cw, zagg, N);
    k_h1<<<dim3((N * 64 + TB - 1) / TB), blk, 0, stream>>>(zagg, W1, b1, bufA, N);

    // layer 2
    k_gemm256<<<dim3((N + 63) / 64, 4), blk, 0, stream>>>(bufA, W2, bufHb, N);
    k_gather_pool<<<dim3((N * 64 + TB - 1) / TB), blk, 0, stream>>>(bufHb, dis, rowptr, csrc, cw,
                                                                    b2, batch, pooled, cntg, N);
    k_final<<<dim3(NG), dim3(64), 0, stream>>>(pooled, cntg, Wout, bout, out, NG);
}